// Round 1
// baseline (260.359 us; speedup 1.0000x reference)
//
#include <hip/hip_runtime.h>
#include <cmath>

#define TW 32
#define TH 64
#define HALO 10
#define HC (TW + HALO)   // 42 halo cols
#define HR (TH + HALO)   // 74 halo rows
#define HCP 44           // padded float2 row stride (16B-aligned rows)
#define IMG 512
#define SSIM_C1 1e-4f
#define SSIM_C2 9e-4f

struct GaussWin { float g[11]; };

// Tile kernel: separable 11x11 Gaussian over 5 fields (x, y, x^2, y^2, xy),
// SSIM epilogue, conf weighting, per-block partial sum.
__launch_bounds__(256, 2)
__global__ void ssim_tile_kernel(const float* __restrict__ x,
                                 const float* __restrict__ y,
                                 const float* __restrict__ conf,
                                 float* __restrict__ partials,
                                 float* __restrict__ out,   // used only if !use_ws
                                 int use_ws, float scale,
                                 GaussWin W) {
    __shared__ float2 s_xy[HR * HCP];   // 26048 B
    __shared__ float4 s_h4[HR * TW];    // 37888 B  (sx, sy, sxx, syy)
    __shared__ float  s_h1[HR * TW];    //  9472 B  (sxy)
    __shared__ float  s_red[4];

    const int tid = threadIdx.x;
    const int plane = blockIdx.z;              // b*3 + c
    const int tx0 = blockIdx.x * TW;
    const int ty0 = blockIdx.y * TH;
    const int pbase = plane * (IMG * IMG);
    const int cbase = (plane / 3) * (IMG * IMG);

    // ---- Phase 0: load halo tile (zero padding at image borders) ----
    for (int i = tid; i < HR * HC; i += 256) {
        int r = i / HC, c = i - r * HC;
        int gy = ty0 - 5 + r, gx = tx0 - 5 + c;
        float xv = 0.f, yv = 0.f;
        if ((unsigned)gy < IMG && (unsigned)gx < IMG) {
            int idx = pbase + gy * IMG + gx;
            xv = x[idx];
            yv = y[idx];
        }
        s_xy[r * HCP + c] = make_float2(xv, yv);
    }
    __syncthreads();

    // ---- Phase 1: horizontal pass, 8-output strips (register-blocked) ----
    for (int s = tid; s < HR * 4; s += 256) {
        int r = s >> 2;
        int cs = (s & 3) * 8;                 // output cols cs..cs+7
        const float4* src = (const float4*)(&s_xy[r * HCP + cs]); // 16B aligned
        float vx[18], vy[18];
        #pragma unroll
        for (int q = 0; q < 9; q++) {
            float4 f = src[q];                 // two float2s: (x0,y0,x1,y1)
            vx[2*q]   = f.x; vy[2*q]   = f.y;
            vx[2*q+1] = f.z; vy[2*q+1] = f.w;
        }
        float pxx[18], pyy[18], pxy[18];
        #pragma unroll
        for (int k = 0; k < 18; k++) {
            pxx[k] = vx[k] * vx[k];
            pyy[k] = vy[k] * vy[k];
            pxy[k] = vx[k] * vy[k];
        }
        #pragma unroll
        for (int j = 0; j < 8; j++) {
            float sx = 0.f, sy = 0.f, sxx = 0.f, syy = 0.f, sxy = 0.f;
            #pragma unroll
            for (int k = 0; k < 11; k++) {
                float w = W.g[k];
                sx  = fmaf(w, vx[j + k], sx);
                sy  = fmaf(w, vy[j + k], sy);
                sxx = fmaf(w, pxx[j + k], sxx);
                syy = fmaf(w, pyy[j + k], syy);
                sxy = fmaf(w, pxy[j + k], sxy);
            }
            s_h4[r * TW + cs + j] = make_float4(sx, sy, sxx, syy);
            s_h1[r * TW + cs + j] = sxy;
        }
    }
    __syncthreads();

    // ---- Phase 2: vertical pass, 8 vertically-adjacent outputs per thread ----
    const int c  = tid & 31;
    const int r0 = (tid >> 5) * 8;            // 8 groups x 8 rows = 64 rows
    float a0[8], a1[8], a2[8], a3[8], a4[8];
    #pragma unroll
    for (int j = 0; j < 8; j++) { a0[j]=0.f; a1[j]=0.f; a2[j]=0.f; a3[j]=0.f; a4[j]=0.f; }

    #pragma unroll
    for (int t = 0; t < 18; t++) {
        float4 h4 = s_h4[(r0 + t) * TW + c];
        float  h1 = s_h1[(r0 + t) * TW + c];
        #pragma unroll
        for (int j = 0; j < 8; j++) {
            int k = t - j;                    // weight index, constant post-unroll
            if (k >= 0 && k <= 10) {
                float w = W.g[k];
                a0[j] = fmaf(w, h4.x, a0[j]);
                a1[j] = fmaf(w, h4.y, a1[j]);
                a2[j] = fmaf(w, h4.z, a2[j]);
                a3[j] = fmaf(w, h4.w, a3[j]);
                a4[j] = fmaf(w, h1,   a4[j]);
            }
        }
    }

    // ---- Epilogue: SSIM + conf weighting + accumulate ----
    float lsum = 0.f;
    #pragma unroll
    for (int j = 0; j < 8; j++) {
        float mu_x = a0[j], mu_y = a1[j];
        float mu_x2 = mu_x * mu_x;
        float mu_y2 = mu_y * mu_y;
        float mu_xy = mu_x * mu_y;
        float sigx  = a2[j] - mu_x2;
        float sigy  = a3[j] - mu_y2;
        float sigxy = a4[j] - mu_xy;
        float num = (2.f * mu_xy + SSIM_C1) * (2.f * sigxy + SSIM_C2);
        float den = (mu_x2 + mu_y2 + SSIM_C1) * (sigx + sigy + SSIM_C2);
        float ssim = num / den;
        float loss = 1.f - ssim;
        loss = fminf(fmaxf(loss, 0.f), 1.f);
        int gy = ty0 + r0 + j, gx = tx0 + c;
        float cf = conf[cbase + gy * IMG + gx];
        lsum = fmaf(loss, cf, lsum);
    }

    // ---- Block reduction ----
    #pragma unroll
    for (int off = 32; off; off >>= 1) lsum += __shfl_down(lsum, off, 64);
    if ((tid & 63) == 0) s_red[tid >> 6] = lsum;
    __syncthreads();
    if (tid == 0) {
        float t = s_red[0] + s_red[1] + s_red[2] + s_red[3];
        if (use_ws) {
            partials[blockIdx.x + gridDim.x * (blockIdx.y + gridDim.y * blockIdx.z)] = t;
        } else {
            atomicAdd(out, t * scale);
        }
    }
}

__global__ void reduce_kernel(const float* __restrict__ partials, int n,
                              float* __restrict__ out, float scale) {
    __shared__ float s_red[4];
    float s = 0.f;
    for (int i = threadIdx.x; i < n; i += 256) s += partials[i];
    #pragma unroll
    for (int off = 32; off; off >>= 1) s += __shfl_down(s, off, 64);
    if ((threadIdx.x & 63) == 0) s_red[threadIdx.x >> 6] = s;
    __syncthreads();
    if (threadIdx.x == 0) out[0] = (s_red[0] + s_red[1] + s_red[2] + s_red[3]) * scale;
}

extern "C" void kernel_launch(void* const* d_in, const int* in_sizes, int n_in,
                              void* d_out, int out_size, void* d_ws, size_t ws_size,
                              hipStream_t stream) {
    const float* x    = (const float*)d_in[0];
    const float* y    = (const float*)d_in[1];
    const float* conf = (const float*)d_in[2];
    float* out = (float*)d_out;
    float* partials = (float*)d_ws;

    // Gaussian window, computed like the reference: float64 exp + normalize, cast f32
    GaussWin W;
    {
        double gd[11], s = 0.0;
        for (int i = 0; i < 11; i++) { gd[i] = exp(-((i - 5) * (i - 5)) / 4.5); s += gd[i]; }
        for (int i = 0; i < 11; i++) W.g[i] = (float)(gd[i] / s);
    }

    const int B = 16, C = 3;
    const float scale = 1.0f / (float)(B * C * IMG * IMG);  // 1/12582912
    dim3 grid(IMG / TW, IMG / TH, B * C);                   // 16 x 8 x 48 = 6144 blocks
    const int nblocks = (IMG / TW) * (IMG / TH) * B * C;
    const int use_ws = (ws_size >= (size_t)nblocks * sizeof(float)) ? 1 : 0;

    if (!use_ws) {
        // fallback: atomic accumulation into d_out (must zero it first)
        hipMemsetAsync(d_out, 0, sizeof(float), stream);
    }
    ssim_tile_kernel<<<grid, 256, 0, stream>>>(x, y, conf, partials, out, use_ws, scale, W);
    if (use_ws) {
        reduce_kernel<<<1, 256, 0, stream>>>(partials, nblocks, out, scale);
    }
}

// Round 2
// 192.805 us; speedup vs baseline: 1.3504x; 1.3504x over previous
//
#include <hip/hip_runtime.h>
#include <cmath>

#define TW 32
#define TH 64
#define HR (TH + 10)     // 74 rows of h-pass results
#define IMG 512
#define SSIM_C1 1e-4f
#define SSIM_C2 9e-4f

struct GaussWin { float g[11]; };

// Bank-decorrelating column swizzle. Bijective on [0,32) for fixed row.
// Phase-1: 4 lanes writing cols {0,8,16,24}+j at the same time now land in
// 4 different bank quads (the +2*(col>>3) term), and the two r-parities in an
// 8-lane LDS cycle group land 4 banks apart (the +4*row term) -> conflict-free.
// Phase-2: per-row bijection keeps lane->bank a full 32-bank permutation.
__device__ __forceinline__ int swz(int col, int row) {
    return (col & 24) | ((col + 2 * (col >> 3) + 4 * row) & 7);
}

__launch_bounds__(256, 3)
__global__ void ssim_tile_kernel(const float* __restrict__ x,
                                 const float* __restrict__ y,
                                 const float* __restrict__ conf,
                                 float* __restrict__ partials,
                                 float* __restrict__ out,
                                 int use_ws, float scale,
                                 GaussWin W) {
    __shared__ float4 s_h4[HR * TW];    // 37888 B  (sx, sy, sxx, syy)
    __shared__ float  s_h1[HR * TW];    //  9472 B  (sxy)
    __shared__ float  s_red[4];

    const int tid = threadIdx.x;
    const int plane = blockIdx.z;              // b*3 + c
    const int tx0 = blockIdx.x * TW;
    const int ty0 = blockIdx.y * TH;
    const int pbase = plane * (IMG * IMG);
    const int cbase = (plane / 3) * (IMG * IMG);

    // ---- Phase 1: horizontal pass, direct from global (no input staging) ----
    // 74 rows x 4 col-groups = 296 strips; each strip = 8 output cols.
    // Reads 6 aligned float4s per array covering cols [cs-8, cs+16) rel tile;
    // window indices 3..20 are the 18 taps needed. With IMG=512 and 16B-aligned
    // reads, every float4 is either fully in-bounds or fully out (-> zeros),
    // which reproduces the reference's zero padding exactly.
    for (int s = tid; s < HR * 4; s += 256) {
        int r = s >> 2;
        int cs = (s & 3) * 8;
        int gy = ty0 - 5 + r;
        bool rowok = ((unsigned)gy < IMG);
        const float* xrow = x + pbase + gy * IMG;
        const float* yrow = y + pbase + gy * IMG;
        int c0 = tx0 + cs - 8;

        float vx[24], vy[24];
        #pragma unroll
        for (int q = 0; q < 6; q++) {
            int col = c0 + 4 * q;
            float4 fx = make_float4(0.f, 0.f, 0.f, 0.f);
            float4 fy = make_float4(0.f, 0.f, 0.f, 0.f);
            if (rowok && (unsigned)col <= (unsigned)(IMG - 4)) {
                fx = *(const float4*)(xrow + col);
                fy = *(const float4*)(yrow + col);
            }
            vx[4*q+0] = fx.x; vx[4*q+1] = fx.y; vx[4*q+2] = fx.z; vx[4*q+3] = fx.w;
            vy[4*q+0] = fy.x; vy[4*q+1] = fy.y; vy[4*q+2] = fy.z; vy[4*q+3] = fy.w;
        }

        float pxx[18], pyy[18], pxy[18];
        #pragma unroll
        for (int k = 0; k < 18; k++) {
            float a = vx[k + 3], b = vy[k + 3];
            pxx[k] = a * a;
            pyy[k] = b * b;
            pxy[k] = a * b;
        }
        #pragma unroll
        for (int j = 0; j < 8; j++) {
            float sx = 0.f, sy = 0.f, sxx = 0.f, syy = 0.f, sxy = 0.f;
            #pragma unroll
            for (int k = 0; k < 11; k++) {
                float w = W.g[k];
                sx  = fmaf(w, vx[j + k + 3], sx);
                sy  = fmaf(w, vy[j + k + 3], sy);
                sxx = fmaf(w, pxx[j + k], sxx);
                syy = fmaf(w, pyy[j + k], syy);
                sxy = fmaf(w, pxy[j + k], sxy);
            }
            int pc = swz(cs + j, r);
            s_h4[r * TW + pc] = make_float4(sx, sy, sxx, syy);
            s_h1[r * TW + pc] = sxy;
        }
    }
    __syncthreads();

    // ---- Phase 2: vertical pass, 8 vertically-adjacent outputs per thread ----
    const int c  = tid & 31;
    const int r0 = (tid >> 5) * 8;            // 8 groups x 8 rows = 64 rows
    float a0[8], a1[8], a2[8], a3[8], a4[8];
    #pragma unroll
    for (int j = 0; j < 8; j++) { a0[j]=0.f; a1[j]=0.f; a2[j]=0.f; a3[j]=0.f; a4[j]=0.f; }

    #pragma unroll
    for (int t = 0; t < 18; t++) {
        int row = r0 + t;
        int pc = swz(c, row);
        float4 h4 = s_h4[row * TW + pc];
        float  h1 = s_h1[row * TW + pc];
        #pragma unroll
        for (int j = 0; j < 8; j++) {
            int k = t - j;                    // weight index, constant post-unroll
            if (k >= 0 && k <= 10) {
                float w = W.g[k];
                a0[j] = fmaf(w, h4.x, a0[j]);
                a1[j] = fmaf(w, h4.y, a1[j]);
                a2[j] = fmaf(w, h4.z, a2[j]);
                a3[j] = fmaf(w, h4.w, a3[j]);
                a4[j] = fmaf(w, h1,   a4[j]);
            }
        }
    }

    // ---- Epilogue: SSIM + conf weighting + accumulate ----
    float lsum = 0.f;
    #pragma unroll
    for (int j = 0; j < 8; j++) {
        float mu_x = a0[j], mu_y = a1[j];
        float mu_x2 = mu_x * mu_x;
        float mu_y2 = mu_y * mu_y;
        float mu_xy = mu_x * mu_y;
        float sigx  = a2[j] - mu_x2;
        float sigy  = a3[j] - mu_y2;
        float sigxy = a4[j] - mu_xy;
        float num = (2.f * mu_xy + SSIM_C1) * (2.f * sigxy + SSIM_C2);
        float den = (mu_x2 + mu_y2 + SSIM_C1) * (sigx + sigy + SSIM_C2);
        float ssim = num / den;
        float loss = 1.f - ssim;
        loss = fminf(fmaxf(loss, 0.f), 1.f);
        int gy = ty0 + r0 + j, gx = tx0 + c;
        float cf = conf[cbase + gy * IMG + gx];
        lsum = fmaf(loss, cf, lsum);
    }

    // ---- Block reduction ----
    #pragma unroll
    for (int off = 32; off; off >>= 1) lsum += __shfl_down(lsum, off, 64);
    if ((tid & 63) == 0) s_red[tid >> 6] = lsum;
    __syncthreads();
    if (tid == 0) {
        float t = s_red[0] + s_red[1] + s_red[2] + s_red[3];
        if (use_ws) {
            partials[blockIdx.x + gridDim.x * (blockIdx.y + gridDim.y * blockIdx.z)] = t;
        } else {
            atomicAdd(out, t * scale);
        }
    }
}

__global__ void reduce_kernel(const float* __restrict__ partials, int n,
                              float* __restrict__ out, float scale) {
    __shared__ float s_red[4];
    float s = 0.f;
    for (int i = blockIdx.x * 256 + threadIdx.x; i < n; i += gridDim.x * 256)
        s += partials[i];
    #pragma unroll
    for (int off = 32; off; off >>= 1) s += __shfl_down(s, off, 64);
    if ((threadIdx.x & 63) == 0) s_red[threadIdx.x >> 6] = s;
    __syncthreads();
    if (threadIdx.x == 0) {
        float t = (s_red[0] + s_red[1] + s_red[2] + s_red[3]) * scale;
        atomicAdd(out, t);
    }
}

extern "C" void kernel_launch(void* const* d_in, const int* in_sizes, int n_in,
                              void* d_out, int out_size, void* d_ws, size_t ws_size,
                              hipStream_t stream) {
    const float* x    = (const float*)d_in[0];
    const float* y    = (const float*)d_in[1];
    const float* conf = (const float*)d_in[2];
    float* out = (float*)d_out;
    float* partials = (float*)d_ws;

    // Gaussian window, computed like the reference: float64 exp + normalize, cast f32
    GaussWin W;
    {
        double gd[11], s = 0.0;
        for (int i = 0; i < 11; i++) { gd[i] = exp(-((i - 5) * (i - 5)) / 4.5); s += gd[i]; }
        for (int i = 0; i < 11; i++) W.g[i] = (float)(gd[i] / s);
    }

    const int B = 16, C = 3;
    const float scale = 1.0f / (float)(B * C * IMG * IMG);
    dim3 grid(IMG / TW, IMG / TH, B * C);                   // 16 x 8 x 48 = 6144 blocks
    const int nblocks = (IMG / TW) * (IMG / TH) * B * C;
    const int use_ws = (ws_size >= (size_t)nblocks * sizeof(float)) ? 1 : 0;

    // d_out is poisoned before every timed launch; both paths accumulate via
    // atomics, so zero it on the stream (memset nodes are graph-capturable).
    hipMemsetAsync(d_out, 0, sizeof(float), stream);
    ssim_tile_kernel<<<grid, 256, 0, stream>>>(x, y, conf, partials, out, use_ws, scale, W);
    if (use_ws) {
        reduce_kernel<<<16, 256, 0, stream>>>(partials, nblocks, out, scale);
    }
}